// Round 16
// baseline (16618.024 us; speedup 1.0000x reference)
//
#include <hip/hip_runtime.h>
#include <hip/hip_fp16.h>
#include <math.h>

// EarthMoverDistance: exact Hungarian (JV successive shortest path).
// B=8, N=1024, 3-D Euclidean cost. SSP: one wave per batch; lane owns 16
// columns (c = lane*16+k) in registers.
// R22 (base = R21, 15.50 ms; AUCTION BYTE-IDENTICAL — jv-only round):
//  - R21 closed the auction lever: phase-deepening now trades ~1:1 with
//    auction cost (totals flat R18/R20/R21). jv floor ~13.0 ms at ~780
//    cy/settle; unavoidable compute ~300 cy => ~480 cy is L2 miss latency
//    when the single runner-up prediction misses.
//  - jv: TWO-SLOT speculative prefetch (runner-up + third-best). The
//    extra wave-min+ballot for the third candidate hides under the
//    winner's L2 load like the existing runner-up logic. NOT R14's
//    pipeline: no Frag copies in the tie loop, settle body unchanged
//    except the hit check (pred2/P2) and the prediction block.
//  - Hard requirement: WRITE_SIZE stays ~0.25 KB (no spill; +1 Frag =
//    ~+10 VGPR). If jv flat => per-settle is compute-bound; argmin chain
//    becomes the endgame.
// Correctness: predictions are pure perf hints (hit => same data as a
// fresh load of the same constant row + u_lds unchanged within a search).
// fp16 cost matrix in d_ws (2 MB/batch, XCD-L2 resident); FINAL SUM
// recomputed in fp32 from coords (absmax 0.0 across R6-R21 variants).

#define N     1024
#define BATCH 8
#define NSLOT 16          // columns per lane (SSP)
#define INFV  1e9f
#define AUC_R1 32         // initial bidding rounds
#define AUC_RP 12         // rounds per drop-rebid phase
#define AUC_PHASES 20     // drop-rebid phases (convergence exit only)

__global__ void emd_zero_kernel(float* out) { out[0] = 0.0f; }

// ---- cost cache: D[b][r][c] = fp16(dist(S1[b][r], S2[b][c])) ----
__global__ __launch_bounds__(256)
void emd_dist_kernel(const float* __restrict__ S1, const float* __restrict__ S2,
                     __half* __restrict__ D) {
    int b = blockIdx.x >> 10;
    int r = blockIdx.x & (N - 1);
    const float* s1 = S1 + ((size_t)b * N + r) * 3;
    float x1 = s1[0], y1 = s1[1], z1 = s1[2];
    const float* s2 = S2 + (size_t)b * N * 3;
    __half* drow = D + ((size_t)b * N + r) * (size_t)N;
    for (int c = threadIdx.x; c < N; c += 256) {
        float dx = x1 - s2[3 * c], dy = y1 - s2[3 * c + 1], dz = z1 - s2[3 * c + 2];
        drow[c] = __float2half_rn(sqrtf(dx * dx + dy * dy + dz * dz));
    }
}

// ---- column reduction over the fp16 matrix: v[c] = min_r C'(r,c) ----
__global__ __launch_bounds__(256)
void emd_colmin_kernel(const __half* __restrict__ D, float* __restrict__ V,
                       int* __restrict__ I) {
    int b = blockIdx.x >> 2;
    int c = ((blockIdx.x & 3) << 8) + threadIdx.x;
    const __half* Db = D + ((size_t)b << 20);
    float best = INFV; int bi = 1;
    for (int r = 0; r < N; ++r) {
        float d = __half2float(Db[(size_t)r * N + c]);
        if (d < best) { best = d; bi = r + 1; }
    }
    V[b * N + c] = best;
    I[b * N + c] = bi;
}

template<int CTRL>
__device__ __forceinline__ float dppmin(float x) {
    int xi = __float_as_int(x);
    int yi = __builtin_amdgcn_update_dpp(xi, xi, CTRL, 0xF, 0xF, false);
    return fminf(x, __int_as_float(yi));
}

__device__ __forceinline__ float wave_min_f32(float x) {
    x = dppmin<0x111>(x);   // row_shr:1
    x = dppmin<0x112>(x);   // row_shr:2
    x = dppmin<0x114>(x);   // row_shr:4
    x = dppmin<0x118>(x);   // row_shr:8
    x = dppmin<0x142>(x);   // row_bcast:15
    x = dppmin<0x143>(x);   // row_bcast:31 -> lane 63 has global min
    return __int_as_float(__builtin_amdgcn_readlane(__float_as_int(x), 63));
}

// ---- parallel auction initializer: 1024 threads (16 waves) per batch ----
// Invariants on exit (enforced by final u-fixup): red(i,j)=C'(i,j)-u_i-v_j
// >= 0 for all i,j (u_i = rowmin); red == 0 on every kept match.
// v stored TRANSPOSED in LDS: v0T[k*64 + lane] = v[lane*16 + k]
// (column c: owner lane = c>>4, slot k = c&15 -> v0T[(c&15)*64 + (c>>4)]).
__global__ __launch_bounds__(1024, 1)
void emd_auction_kernel(const __half* __restrict__ Dc,
                        const float* __restrict__ Vin,
                        const int* __restrict__ Iin,
                        float* __restrict__ Vw, float* __restrict__ Uw,
                        int* __restrict__ Cw, int* __restrict__ Rw) {
    __shared__ float v0T[N];                // column potentials, TRANSPOSED
    __shared__ int   rowm[N + 1];           // row -> col (1-idx), 0 = free
    __shared__ int   colm[N + 1];           // col -> row (1-idx), 0 = free
    __shared__ unsigned long long bid[N + 1];
    __shared__ int   qbuf[N];
    __shared__ int   qn;

    const int tid  = threadIdx.x;
    const int lane = tid & 63;
    const int wv   = tid >> 6;              // wave id 0..15
    const int b    = blockIdx.x;
    const __half* Db = Dc + ((size_t)b << 20);

    for (int t = tid; t <= N; t += 1024) { rowm[t] = 0; colm[t] = 0; bid[t] = 0ull; }
    for (int c = tid; c < N; c += 1024)
        v0T[(c & 15) * 64 + (c >> 4)] = Vin[b * N + c];
    __syncthreads();

    // greedy on tight edges (column -> its argmin row from colmin kernel)
    for (int c = tid; c < N; c += 1024) {
        int r = Iin[b * N + c];             // 1-indexed row
        int old = atomicCAS(&rowm[r], 0, c + 1);
        if (old == 0) colm[c + 1] = r;
    }
    __syncthreads();

    // ---- raw next-row prefetch cache (cost matrix constant, never stale) ----
    uint4 pw0, pw1; int pi = 0;
    auto prefRow = [&](int rr) {
        const uint4* dr = (const uint4*)(Db + (size_t)(rr - 1) * N);
        pw0 = dr[lane * 2 + 0];
        pw1 = dr[lane * 2 + 1];
        pi = rr;
    };
    // red[k] = C'(i, lane*16+k) - v[lane*16+k]; v via conflict-free
    // transposed reads v0T[k*64+lane].
    auto rowRed16 = [&](int i, float (&red)[16]) {
        uint4 w0, w1;
        if (i == pi) { w0 = pw0; w1 = pw1; }
        else {
            const uint4* dr = (const uint4*)(Db + (size_t)(i - 1) * N);
            w0 = dr[lane * 2 + 0];
            w1 = dr[lane * 2 + 1];
        }
        unsigned wb[8] = { w0.x, w0.y, w0.z, w0.w, w1.x, w1.y, w1.z, w1.w };
#pragma unroll
        for (int t = 0; t < 8; ++t) {
            __half2 hh = *reinterpret_cast<const __half2*>(&wb[t]);
            float2 f2 = __half22float2(hh);
            red[2 * t]     = f2.x - v0T[(2 * t) * 64 + lane];
            red[2 * t + 1] = f2.y - v0T[(2 * t + 1) * 64 + lane];
        }
    };

    // ---- bidding rounds (rbase carries tie-rotation parity across calls) ----
    auto runRounds = [&](int nrounds, int rbase) {
        for (int round = 0; round < nrounds; ++round) {
            if (tid == 0) qn = 0;
            __syncthreads();
            for (int i = tid + 1; i <= N; i += 1024)
                if (rowm[i] == 0) { int p = atomicAdd(&qn, 1); qbuf[p] = i; }
            __syncthreads();
            int nq = qn;
            if (nq == 0) break;

            for (int q = wv; q < nq; q += 16) {
                int i = qbuf[q];
                // this row's load (hit or miss), then issue next scan's
                // prefetch so it flies under the argmin compute.
                float red[16];
                rowRed16(i, red);
                if (q + 16 < nq) prefRow(qbuf[q + 16]);
                // local (min, secmin, argmin-col 0-idx): 4 chains of depth 4
                float a1 = INFV, a2 = INFV; int ac = 0;
                float e1 = INFV, e2 = INFV; int ec = 0;
                float f1 = INFV, f2 = INFV; int fc = 0;
                float g1 = INFV, g2 = INFV; int gc = 0;
#pragma unroll
                for (int k = 0; k < 4; ++k) {
                    float u0 = red[k];
                    bool t0 = u0 < a1;
                    a2 = t0 ? a1 : (u0 < a2 ? u0 : a2);
                    ac = t0 ? (lane * 16 + k) : ac;  a1 = t0 ? u0 : a1;
                    float u1 = red[k + 4];
                    bool t1 = u1 < e1;
                    e2 = t1 ? e1 : (u1 < e2 ? u1 : e2);
                    ec = t1 ? (lane * 16 + k + 4) : ec;  e1 = t1 ? u1 : e1;
                    float u2 = red[k + 8];
                    bool t2 = u2 < f1;
                    f2 = t2 ? f1 : (u2 < f2 ? u2 : f2);
                    fc = t2 ? (lane * 16 + k + 8) : fc;  f1 = t2 ? u2 : f1;
                    float u3 = red[k + 12];
                    bool t3 = u3 < g1;
                    g2 = t3 ? g1 : (u3 < g2 ? u3 : g2);
                    gc = t3 ? (lane * 16 + k + 12) : gc;  g1 = t3 ? u3 : g1;
                }
                bool sae = e1 < a1;
                float ae1 = sae ? e1 : a1; int aec = sae ? ec : ac;
                float ae2 = fminf(fminf(a2, e2), sae ? a1 : e1);
                bool sfg = g1 < f1;
                float fg1 = sfg ? g1 : f1; int fgc = sfg ? gc : fc;
                float fg2 = fminf(fminf(f2, g2), sfg ? f1 : g1);
                bool sall = fg1 < ae1;
                float m1 = sall ? fg1 : ae1;
                int   c1 = sall ? fgc : aec;
                float m2 = fminf(fminf(ae2, fg2), sall ? ae1 : fg1);

                // wave argmin with payload (uniform results on all lanes)
                float gm1 = wave_min_f32(m1);
                unsigned long long wbm = __ballot(m1 == gm1);
                int wl = __ffsll((long long)wbm) - 1;
                float cand2 = (lane == wl) ? m2 : m1;
                float gm2 = wave_min_f32(cand2);
                int gcol;
                if (gm1 < gm2) {
                    gcol = __builtin_amdgcn_readlane(c1, wl);  // unique argmin
                } else {
                    // ties: prefer a FREE tied column; else rotate the
                    // occupied pick (lowest/highest by parity) to break
                    // deterministic displacement 2-cycles.
                    unsigned tmask = 0u;
#pragma unroll
                    for (int k = 0; k < 16; ++k)
                        tmask |= (red[k] == gm1) ? (1u << k) : 0u;
                    unsigned fmask = 0u;
                    unsigned tt = tmask;
                    while (tt) {
                        int k = __ffs((int)tt) - 1;
                        tt &= tt - 1;
                        if (colm[lane * 16 + k + 1] == 0) fmask |= (1u << k);
                    }
                    unsigned long long bf = __ballot(fmask != 0u);
                    if (bf != 0ull) {
                        int l = __ffsll((long long)bf) - 1;
                        unsigned mk = (unsigned)__builtin_amdgcn_readlane((int)fmask, l);
                        gcol = l * 16 + (__ffs((int)mk) - 1);
                    } else if ((rbase + round) & 1) {
                        unsigned long long ba = __ballot(tmask != 0u);
                        int l = 63 - __clzll(ba);               // highest lane
                        unsigned mk = (unsigned)__builtin_amdgcn_readlane((int)tmask, l);
                        gcol = l * 16 + (31 - __clz((int)mk));  // highest col
                    } else {
                        gcol = __builtin_amdgcn_readlane(c1, wl); // lowest col
                    }
                }
                float inc = gm2 - gm1;                          // >= 0

                if (lane == 0) {
                    unsigned long long key =
                        ((unsigned long long)__float_as_uint(inc) << 32) |
                        (unsigned long long)(unsigned)i;
                    atomicMax(&bid[gcol + 1], key);
                }
            }
            __syncthreads();

            // acceptance: column j takes its best bid; displaced row freed
            for (int j = tid + 1; j <= N; j += 1024) {
                unsigned long long bb = bid[j];
                if (bb != 0ull) {
                    bid[j] = 0ull;
                    int i = (int)(unsigned)(bb & 0xFFFFFFFFull);
                    float inc = __uint_as_float((unsigned)(bb >> 32));
                    int old = colm[j];
                    colm[j] = i;
                    rowm[i] = j;
                    if (old) rowm[old] = 0;
                    v0T[((j - 1) & 15) * 64 + ((j - 1) >> 4)] -= inc;
                }
            }
            __syncthreads();
        }
    };

    // drop any non-tight match (red != rowmin), freeing it to re-bid
    auto midFixup = [&]() {
        for (int q = wv; q < N; q += 16) {
            int i = q + 1;
            if (i + 16 <= N) prefRow(i + 16);   // flies under this row's work
            int j = rowm[i];                // wave-uniform (LDS broadcast)
            if (j == 0) continue;
            float red[16];
            rowRed16(i, red);
            int lo = (j - 1) >> 4, kk = (j - 1) & 15;
            float rloc = red[0];
#pragma unroll
            for (int k = 1; k < 16; ++k) if (k == kk) rloc = red[k];
#pragma unroll
            for (int s = 1; s < 16; s <<= 1) {
#pragma unroll
                for (int k = 0; k < 16; k += 2 * s)
                    red[k] = fminf(red[k], red[k + s]);
            }
            float m = wave_min_f32(red[0]);
            float rm = __int_as_float(
                __builtin_amdgcn_readlane(__float_as_int(rloc), lo));
            if (lane == 0 && rm != m) { rowm[i] = 0; colm[j] = 0; }
        }
    };

    // ---- phase schedule: 32 rounds, then 20 x {fixup; conv-exit?; 12} ----
    runRounds(AUC_R1, 0);
    for (int ph = 0; ph < AUC_PHASES; ++ph) {
        midFixup();
        __syncthreads();
        // convergence exit only: complete matching => remaining = no-ops
        if (tid == 0) qn = 0;
        __syncthreads();
        for (int i = tid + 1; i <= N; i += 1024)
            if (rowm[i] == 0) atomicAdd(&qn, 1);
        __syncthreads();
        if (qn == 0) break;
        runRounds(AUC_RP, ph);
    }

    // ---- final u-fixup: u_i = rowmin(red_i); drop non-tight ----
    for (int q = wv; q < N; q += 16) {
        int i = q + 1;
        if (i + 16 <= N) prefRow(i + 16);
        float red[16];
        rowRed16(i, red);
        int j = rowm[i];                    // wave-uniform (LDS broadcast)
        float rloc = red[0];
        int lo = 0, kk = 0;
        if (j) {
            lo = (j - 1) >> 4; kk = (j - 1) & 15;
#pragma unroll
            for (int k = 1; k < 16; ++k) if (k == kk) rloc = red[k];
        }
#pragma unroll
        for (int s = 1; s < 16; s <<= 1) {
#pragma unroll
            for (int k = 0; k < 16; k += 2 * s)
                red[k] = fminf(red[k], red[k + s]);
        }
        float m = wave_min_f32(red[0]);
        if (j) {
            float rm = __int_as_float(
                __builtin_amdgcn_readlane(__float_as_int(rloc), lo));
            if (lane == 0 && rm != m) { rowm[i] = 0; colm[j] = 0; }
        }
        if (lane == 0) Uw[b * N + q] = m;
    }
    __syncthreads();

    // ---- write state for the SSP kernel ----
    for (int c = tid; c < N; c += 1024) {
        Vw[b * N + c] = v0T[(c & 15) * 64 + (c >> 4)];
        Cw[b * N + c] = colm[c + 1];
    }
    for (int t = tid; t < N; t += 1024) Rw[b * N + t] = rowm[t + 1];
}

struct Frag { uint4 w0, w1; float ur; float4 q; };

template<bool CACHED, bool PRE>
__global__ __launch_bounds__(64, 1)
void emd_jv_kernel(const float* __restrict__ S1,
                   const float* __restrict__ S2,
                   const __half* __restrict__ Dc,
                   const float* __restrict__ Vin,
                   const int*   __restrict__ Iin,
                   const float* __restrict__ Uw,
                   const int*   __restrict__ Cw,
                   const int*   __restrict__ Rw,
                   float* __restrict__ out) {
    __shared__ float4 s1u[N + 1];     // row coords (both modes; final fp32 sum)
    __shared__ float  u_lds[N + 1];   // row potentials
    __shared__ float  dentry[N + 1];  // D value when column settled
    __shared__ int    rowm[N + 1];    // row -> matched col (0 = free)

    const int lane = threadIdx.x;
    const int b = blockIdx.x;
    const float* s1g = S1 + (size_t)b * N * 3;
    const float* s2g = S2 + (size_t)b * N * 3;
    const __half* Db = CACHED ? (Dc + ((size_t)b << 20)) : (const __half*)0;
    const float NANF = __int_as_float(0x7fc00000);

    for (int t = lane; t < N; t += 64) {
        s1u[t + 1] = make_float4(s1g[3 * t], s1g[3 * t + 1], s1g[3 * t + 2], 0.0f);
        u_lds[t + 1] = PRE ? Uw[b * N + t] : 0.0f;
        rowm[t + 1] = PRE ? Rw[b * N + t] : 0;
    }
    if (lane == 0) { u_lds[0] = 0.0f; rowm[0] = 0; }

    // ---- per-lane column state: col j = c+1, c = lane*16+k ----
    float v[NSLOT];       // column potentials
    int   pr[NSLOT];      // matched row (0 = free)
    int   jpk[NSLOT];     // packed (pr<<11)|j
    float x2[NSLOT], y2[NSLOT], z2[NSLOT];  // S2 coords (final fp32 sum)

#pragma unroll
    for (int k = 0; k < NSLOT; ++k) {
        int pt = lane * NSLOT + k;
        x2[k] = s2g[3 * pt + 0];
        y2[k] = s2g[3 * pt + 1];
        z2[k] = s2g[3 * pt + 2];
    }

    if constexpr (PRE) {
#pragma unroll
        for (int k = 0; k < NSLOT; ++k) {
            int c = lane * NSLOT + k;
            v[k] = Vin[b * N + c];        // Vin = auction-updated v
            pr[k] = Cw[b * N + c];
            jpk[k] = (pr[k] << 11) | (c + 1);
        }
        __syncthreads();
    } else {
        int imin[NSLOT];
        if constexpr (CACHED) {
#pragma unroll
            for (int k = 0; k < NSLOT; ++k) {
                int c = lane * NSLOT + k;
                v[k] = Vin[b * N + c];
                imin[k] = Iin[b * N + c];
            }
        } else {
#pragma unroll
            for (int k = 0; k < NSLOT; ++k) { v[k] = INFV; imin[k] = 1; }
        }
        __syncthreads();

        if constexpr (!CACHED) {
            for (int r = 1; r <= N; ++r) {
                float4 qq = s1u[r];
#pragma unroll
                for (int k = 0; k < NSLOT; ++k) {
                    float dx = qq.x - x2[k], dy = qq.y - y2[k], dz = qq.z - z2[k];
                    float d2 = dx * dx + dy * dy + dz * dz;
                    bool upd = d2 < v[k];
                    v[k] = upd ? d2 : v[k];
                    imin[k] = upd ? r : imin[k];
                }
            }
#pragma unroll
            for (int k = 0; k < NSLOT; ++k) v[k] = sqrtf(v[k]);
        }

        // greedy matching on tight edges
#pragma unroll
        for (int k = 0; k < NSLOT; ++k) {
            int j = lane * NSLOT + k + 1;
            int r = imin[k];
            int old = atomicCAS(&rowm[r], 0, j);
            pr[k] = (old == 0) ? r : 0;
            jpk[k] = (pr[k] << 11) | j;
        }
        __syncthreads();
    }

    float minv[NSLOT];
    int   way[NSLOT];

    // issue row-r loads (cost-row fragment + u[r]); consumer waits only these
    auto issueLoads = [&](int rr) -> Frag {
        Frag F;
        if (CACHED) {
            const uint4* dr = (const uint4*)(Db + (size_t)(rr - 1) * N);
            F.w0 = dr[lane * 2 + 0];       // 8 halves
            F.w1 = dr[lane * 2 + 1];       // 8 halves
        } else {
            F.q = s1u[rr];
        }
        F.ur = u_lds[rr];
        return F;
    };

    auto applyFrag = [&](const Frag& F, int jpred, float Dh) {
        float base = Dh - F.ur;
        if (CACHED) {
            float h[NSLOT];
            const unsigned* w = (const unsigned*)&F.w0;   // w0,w1 contiguous
#pragma unroll
            for (int t = 0; t < 8; ++t) {
                unsigned word = w[t];
                __half2 hh = *reinterpret_cast<const __half2*>(&word);
                float2 f2 = __half22float2(hh);
                h[2 * t] = f2.x; h[2 * t + 1] = f2.y;
            }
#pragma unroll
            for (int k = 0; k < NSLOT; ++k) {
                float cur = (h[k] - v[k]) + base;
                bool upd = cur < minv[k];         // false for NaN (settled)
                minv[k] = upd ? cur : minv[k];
                way[k] = upd ? jpred : way[k];
            }
        } else {
#pragma unroll
            for (int k = 0; k < NSLOT; ++k) {
                float dx = F.q.x - x2[k], dy = F.q.y - y2[k], dz = F.q.z - z2[k];
                float d = sqrtf(dx * dx + dy * dy + dz * dz);
                float cur = (d - v[k]) + base;
                bool upd = cur < minv[k];
                minv[k] = upd ? cur : minv[k];
                way[k] = upd ? jpred : way[k];
            }
        }
    };

    // ---- successive shortest paths for free rows (exact on C') ----
    for (int i = 1; i <= N; ++i) {
        if (rowm[i] != 0) continue;

        unsigned used = 0u;
        float DT = 0.0f;
        int freecol = 0;
        int pred = 0, pred2 = 0;   // two-slot speculative prefetch
        Frag P, P2;                // only read when pred/pred2 != 0

        Frag F0 = issueLoads(i);          // overlaps minv/way init
#pragma unroll
        for (int k = 0; k < NSLOT; ++k) { minv[k] = INFV; way[k] = 0; }
        applyFrag(F0, 0, 0.0f);

        int guard = 0;
        for (;;) {
            if (++guard > N + 4) break;
            // local argmin: 4 independent depth-4 chains + 2-level merge.
            float b0 = INFV, b1 = INFV, b2 = INFV, b3 = INFV;
            int   p0 = 0, p1 = 0, p2 = 0, p3 = 0;
#pragma unroll
            for (int k = 0; k < 4; ++k) {
                bool t0 = minv[k]      < b0;
                b0 = t0 ? minv[k]      : b0;  p0 = t0 ? jpk[k]      : p0;
                bool t1 = minv[k + 4]  < b1;
                b1 = t1 ? minv[k + 4]  : b1;  p1 = t1 ? jpk[k + 4]  : p1;
                bool t2 = minv[k + 8]  < b2;
                b2 = t2 ? minv[k + 8]  : b2;  p2 = t2 ? jpk[k + 8]  : p2;
                bool t3 = minv[k + 12] < b3;
                b3 = t3 ? minv[k + 12] : b3;  p3 = t3 ? jpk[k + 12] : p3;
            }
            bool m01 = b1 < b0;  float ba = m01 ? b1 : b0;  int pa = m01 ? p1 : p0;
            bool m23 = b3 < b2;  float bb = m23 ? b3 : b2;  int pb = m23 ? p3 : p2;
            bool mab = bb < ba;  float bestv = mab ? bb : ba;
            int bestjp = mab ? pb : pa;

            float gmin = wave_min_f32(bestv);
            if (!(gmin < INFV * 0.5f)) break;
            unsigned long long tm = __ballot(bestv == gmin);
            DT = gmin;
            freecol = 0;

            // 1) free-column short-circuit: single ballot (equivalent to
            //    scanning ties lowest-lane-first for a free bestjp)
            {
                unsigned long long tf =
                    __ballot((bestv == gmin) && ((bestjp >> 11) == 0));
                if (tf) {
                    int l = __ffsll((long long)tf) - 1;
                    freecol = __builtin_amdgcn_readlane(bestjp, l) & 0x7FF;
                }
            }
            if (freecol) break;

            // 2) settle all matched ties at gmin
            bool first = true;
            while (tm) {
                int l = __ffsll((long long)tm) - 1;
                tm &= tm - 1;
                int jp = __builtin_amdgcn_readlane(bestjp, l);
                int jj = jp & 0x7FF, rr = jp >> 11;
                Frag F;
                if (CACHED && first && pred != 0 && rr == pred) {
                    F = P;                         // slot-1 hit
                } else if (CACHED && first && pred2 != 0 && rr == pred2) {
                    F = P2;                        // slot-2 hit
                } else {
                    F = issueLoads(rr);            // loads fly during marking
                }
                if (CACHED && first) {
                    // two-slot prediction for the NEXT round: runner-up and
                    // third-best candidate rows. All wave-mins + ballots here
                    // hide under the winner's L2 load latency. (u_lds is
                    // constant during a search -> cached rows stay valid.)
                    float ru = (bestv == gmin) ? INFV : bestv;
                    float rmin = wave_min_f32(ru);
                    pred = 0; pred2 = 0;
                    if (rmin < INFV * 0.5f) {
                        unsigned long long rb = __ballot(ru == rmin);
                        int rl = __ffsll((long long)rb) - 1;
                        int rjp = __builtin_amdgcn_readlane(bestjp, rl);
                        int prr = rjp >> 11;
                        if (prr != 0) { pred = prr; P = issueLoads(prr); }
                        // third-best: mask the runner-up value class too
                        float ru2 = (ru == rmin) ? INFV : ru;
                        float rmin2 = wave_min_f32(ru2);
                        if (rmin2 < INFV * 0.5f) {
                            unsigned long long rb2 = __ballot(ru2 == rmin2);
                            int rl2 = __ffsll((long long)rb2) - 1;
                            int rjp2 = __builtin_amdgcn_readlane(bestjp, rl2);
                            int prr2 = rjp2 >> 11;
                            if (prr2 != 0 && prr2 != pred) {
                                pred2 = prr2; P2 = issueLoads(prr2);
                            }
                        }
                    }
                }
                first = false;
                if (lane == 0) dentry[jj] = gmin;
                int cc = jj - 1, lo = cc >> 4, kk = cc & 15;
                bool mine = (lane == lo);
#pragma unroll
                for (int k = 0; k < NSLOT; ++k)
                    if (k == kk && mine) { minv[k] = NANF; used |= (1u << k); }
                applyFrag(F, jj, gmin);
            }
        }
        if (freecol == 0) continue;

        // deferred dual updates (pre-augment pr)
        if (lane == 0) u_lds[i] += DT;
#pragma unroll
        for (int k = 0; k < NSLOT; ++k) {
            if ((used >> k) & 1u) {
                int j = lane * NSLOT + k + 1;
                float dd = DT - dentry[j];
                v[k] -= dd;
                u_lds[pr[k]] += dd;      // distinct rows: race-free
            }
        }
        __syncthreads();

        // augment along alternating path (register p via readlanes)
        int j0 = freecol;
        int aguard = 0;
        while (j0 != 0) {
            if (++aguard > N + 4) break;
            int cc = j0 - 1;
            int lo = cc >> 4, kk = cc & 15;
            int wloc = way[0];
#pragma unroll
            for (int k = 1; k < NSLOT; ++k) if (k == kk) wloc = way[k];
            int j1 = __builtin_amdgcn_readlane(wloc, lo);
            int np;
            if (j1 == 0) np = i;
            else {
                int c1 = j1 - 1;
                int lo1 = c1 >> 4, kk1 = c1 & 15;
                int ploc = pr[0];
#pragma unroll
                for (int k = 1; k < NSLOT; ++k) if (k == kk1) ploc = pr[k];
                np = __builtin_amdgcn_readlane(ploc, lo1);
            }
            bool mine = (lane == lo);
#pragma unroll
            for (int k = 0; k < NSLOT; ++k)
                if (k == kk) {
                    if (mine) { pr[k] = np; jpk[k] = (np << 11) | j0; }
                }
            if (lane == 0) rowm[np] = j0;
            j0 = j1;
        }
        __syncthreads();
    }

    // ---- total matched cost: exact fp32 from coordinates ----
    float sum = 0.0f;
#pragma unroll
    for (int k = 0; k < NSLOT; ++k) {
        int r = pr[k] > 0 ? pr[k] : 1;
        float4 qq = s1u[r];
        float dx = qq.x - x2[k], dy = qq.y - y2[k], dz = qq.z - z2[k];
        sum += sqrtf(dx * dx + dy * dy + dz * dz);
    }
#pragma unroll
    for (int off = 32; off >= 1; off >>= 1) sum += __shfl_xor(sum, off);
    if (lane == 0) atomicAdd(out, sum * (1.0f / ((float)N * (float)BATCH)));
}

extern "C" void kernel_launch(void* const* d_in, const int* in_sizes, int n_in,
                              void* d_out, int out_size, void* d_ws, size_t ws_size,
                              hipStream_t stream) {
    const float* S1 = (const float*)d_in[0];
    const float* S2 = (const float*)d_in[1];
    float* out = (float*)d_out;

    size_t needD  = (size_t)BATCH * N * N * sizeof(__half);
    size_t vecB   = (size_t)BATCH * N * 4;            // one per-col/per-row array
    size_t needT  = needD + 2 * vecB;                 // V + I            (R8 tier)
    size_t needT2 = needD + 6 * vecB;                 // + Vw,Uw,Cw,Rw    (R13 tier)

    emd_zero_kernel<<<1, 1, 0, stream>>>(out);

    if (ws_size >= needT2) {
        __half* D  = (__half*)d_ws;
        float*  V  = (float*)((char*)d_ws + needD);
        int*    I  = (int*)((char*)V + vecB);
        float*  Vw = (float*)((char*)I + vecB);
        float*  Uw = (float*)((char*)Vw + vecB);
        int*    Cw = (int*)((char*)Uw + vecB);
        int*    Rw = (int*)((char*)Cw + vecB);
        emd_dist_kernel<<<BATCH * N, 256, 0, stream>>>(S1, S2, D);
        emd_colmin_kernel<<<BATCH * 4, 256, 0, stream>>>(D, V, I);
        emd_auction_kernel<<<BATCH, 1024, 0, stream>>>(D, V, I, Vw, Uw, Cw, Rw);
        emd_jv_kernel<true, true><<<BATCH, 64, 0, stream>>>(
            S1, S2, D, Vw, nullptr, Uw, Cw, Rw, out);
    } else if (ws_size >= needT) {
        __half* D = (__half*)d_ws;
        float*  V = (float*)((char*)d_ws + needD);
        int*    I = (int*)((char*)V + vecB);
        emd_dist_kernel<<<BATCH * N, 256, 0, stream>>>(S1, S2, D);
        emd_colmin_kernel<<<BATCH * 4, 256, 0, stream>>>(D, V, I);
        emd_jv_kernel<true, false><<<BATCH, 64, 0, stream>>>(
            S1, S2, D, V, I, nullptr, nullptr, nullptr, out);
    } else {
        emd_jv_kernel<false, false><<<BATCH, 64, 0, stream>>>(
            S1, S2, nullptr, nullptr, nullptr, nullptr, nullptr, nullptr, out);
    }
}

// Round 18
// 15577.814 us; speedup vs baseline: 1.0668x; 1.0668x over previous
//
#include <hip/hip_runtime.h>
#include <hip/hip_fp16.h>
#include <math.h>

// EarthMoverDistance: exact Hungarian (JV successive shortest path).
// B=8, N=1024, 3-D Euclidean cost. SSP: one wave per batch; lane owns 16
// columns (c = lane*16+k) in registers.
// R24 (= R23 resubmitted; previous round was an infra failure, no signal):
//  - jv = R21 BYTE-IDENTICAL (proven ~13.0 ms floor; R14/R22 showed the
//    settle loop rejects micro-surgery).
//  - Auction: BALLOT-BASED QUEUE COMPACTION. The per-round qbuf build was
//    up to 1024 serialized atomicAdd to one LDS address (~2-4us/round x
//    ~270 rounds ~ 1ms). With block=1024=N each thread owns row tid+1:
//    per-wave ballot+popcount prefix, 16 wave counts in LDS, register
//    prefix across waves. Outcome-neutral (queue order only maps rows to
//    waves; bids are pure reads, acceptance via atomicMax as before).
//    Same pattern replaces the convergence-check count. Barriers inside
//    buildQueue are uniform (all threads reach them; loop bounds are
//    block-uniform LDS-derived values).
//  Correctness unconditional (R16-R21): prices only decrease => red >= 0;
//  final u-fixup enforces red == rowmin on kept matches; SSP exact.
// fp16 cost matrix in d_ws (2 MB/batch, XCD-L2 resident); FINAL SUM
// recomputed in fp32 from coords (absmax 0.0 across R6-R22 variants).

#define N     1024
#define BATCH 8
#define NSLOT 16          // columns per lane (SSP)
#define INFV  1e9f
#define AUC_R1 32         // initial bidding rounds
#define AUC_RP 12         // rounds per drop-rebid phase
#define AUC_PHASES 20     // drop-rebid phases (convergence exit only)

__global__ void emd_zero_kernel(float* out) { out[0] = 0.0f; }

// ---- cost cache: D[b][r][c] = fp16(dist(S1[b][r], S2[b][c])) ----
__global__ __launch_bounds__(256)
void emd_dist_kernel(const float* __restrict__ S1, const float* __restrict__ S2,
                     __half* __restrict__ D) {
    int b = blockIdx.x >> 10;
    int r = blockIdx.x & (N - 1);
    const float* s1 = S1 + ((size_t)b * N + r) * 3;
    float x1 = s1[0], y1 = s1[1], z1 = s1[2];
    const float* s2 = S2 + (size_t)b * N * 3;
    __half* drow = D + ((size_t)b * N + r) * (size_t)N;
    for (int c = threadIdx.x; c < N; c += 256) {
        float dx = x1 - s2[3 * c], dy = y1 - s2[3 * c + 1], dz = z1 - s2[3 * c + 2];
        drow[c] = __float2half_rn(sqrtf(dx * dx + dy * dy + dz * dz));
    }
}

// ---- column reduction over the fp16 matrix: v[c] = min_r C'(r,c) ----
__global__ __launch_bounds__(256)
void emd_colmin_kernel(const __half* __restrict__ D, float* __restrict__ V,
                       int* __restrict__ I) {
    int b = blockIdx.x >> 2;
    int c = ((blockIdx.x & 3) << 8) + threadIdx.x;
    const __half* Db = D + ((size_t)b << 20);
    float best = INFV; int bi = 1;
    for (int r = 0; r < N; ++r) {
        float d = __half2float(Db[(size_t)r * N + c]);
        if (d < best) { best = d; bi = r + 1; }
    }
    V[b * N + c] = best;
    I[b * N + c] = bi;
}

template<int CTRL>
__device__ __forceinline__ float dppmin(float x) {
    int xi = __float_as_int(x);
    int yi = __builtin_amdgcn_update_dpp(xi, xi, CTRL, 0xF, 0xF, false);
    return fminf(x, __int_as_float(yi));
}

__device__ __forceinline__ float wave_min_f32(float x) {
    x = dppmin<0x111>(x);   // row_shr:1
    x = dppmin<0x112>(x);   // row_shr:2
    x = dppmin<0x114>(x);   // row_shr:4
    x = dppmin<0x118>(x);   // row_shr:8
    x = dppmin<0x142>(x);   // row_bcast:15
    x = dppmin<0x143>(x);   // row_bcast:31 -> lane 63 has global min
    return __int_as_float(__builtin_amdgcn_readlane(__float_as_int(x), 63));
}

// ---- parallel auction initializer: 1024 threads (16 waves) per batch ----
// Invariants on exit (enforced by final u-fixup): red(i,j)=C'(i,j)-u_i-v_j
// >= 0 for all i,j (u_i = rowmin); red == 0 on every kept match.
// v stored TRANSPOSED in LDS: v0T[k*64 + lane] = v[lane*16 + k].
__global__ __launch_bounds__(1024, 1)
void emd_auction_kernel(const __half* __restrict__ Dc,
                        const float* __restrict__ Vin,
                        const int* __restrict__ Iin,
                        float* __restrict__ Vw, float* __restrict__ Uw,
                        int* __restrict__ Cw, int* __restrict__ Rw) {
    __shared__ float v0T[N];                // column potentials, TRANSPOSED
    __shared__ int   rowm[N + 1];           // row -> col (1-idx), 0 = free
    __shared__ int   colm[N + 1];           // col -> row (1-idx), 0 = free
    __shared__ unsigned long long bid[N + 1];
    __shared__ int   qbuf[N];
    __shared__ int   wcnt[16];              // per-wave free counts (compaction)

    const int tid  = threadIdx.x;
    const int lane = tid & 63;
    const int wv   = tid >> 6;              // wave id 0..15
    const int b    = blockIdx.x;
    const __half* Db = Dc + ((size_t)b << 20);

    for (int t = tid; t <= N; t += 1024) { rowm[t] = 0; colm[t] = 0; bid[t] = 0ull; }
    for (int c = tid; c < N; c += 1024)
        v0T[(c & 15) * 64 + (c >> 4)] = Vin[b * N + c];
    __syncthreads();

    // greedy on tight edges (column -> its argmin row from colmin kernel)
    for (int c = tid; c < N; c += 1024) {
        int r = Iin[b * N + c];             // 1-indexed row
        int old = atomicCAS(&rowm[r], 0, c + 1);
        if (old == 0) colm[c + 1] = r;
    }
    __syncthreads();

    // ballot-based free-row queue build: each thread owns row tid+1.
    // Returns nq (uniform); fills qbuf[0..nq). Outcome-neutral vs the
    // old atomicAdd build (order only maps rows to waves; bids are pure
    // reads of post-barrier state). Barriers uniform: all threads call.
    auto buildQueue = [&]() -> int {
        int i = tid + 1;
        bool fr = (rowm[i] == 0);
        unsigned long long mb = __ballot(fr);
        int pre = __popcll(mb & ((1ull << lane) - 1ull));
        if (lane == 0) wcnt[wv] = __popcll(mb);
        __syncthreads();
        int base = 0, nq = 0;
#pragma unroll
        for (int w = 0; w < 16; ++w) {
            int c = wcnt[w];
            base += (w < wv) ? c : 0;
            nq += c;
        }
        if (fr) qbuf[base + pre] = i;
        __syncthreads();
        return nq;
    };

    // ---- raw next-row prefetch cache (cost matrix constant, never stale) ----
    uint4 pw0, pw1; int pi = 0;
    auto prefRow = [&](int rr) {
        const uint4* dr = (const uint4*)(Db + (size_t)(rr - 1) * N);
        pw0 = dr[lane * 2 + 0];
        pw1 = dr[lane * 2 + 1];
        pi = rr;
    };
    // red[k] = C'(i, lane*16+k) - v[lane*16+k]; conflict-free transposed v.
    auto rowRed16 = [&](int i, float (&red)[16]) {
        uint4 w0, w1;
        if (i == pi) { w0 = pw0; w1 = pw1; }
        else {
            const uint4* dr = (const uint4*)(Db + (size_t)(i - 1) * N);
            w0 = dr[lane * 2 + 0];
            w1 = dr[lane * 2 + 1];
        }
        unsigned wb[8] = { w0.x, w0.y, w0.z, w0.w, w1.x, w1.y, w1.z, w1.w };
#pragma unroll
        for (int t = 0; t < 8; ++t) {
            __half2 hh = *reinterpret_cast<const __half2*>(&wb[t]);
            float2 f2 = __half22float2(hh);
            red[2 * t]     = f2.x - v0T[(2 * t) * 64 + lane];
            red[2 * t + 1] = f2.y - v0T[(2 * t + 1) * 64 + lane];
        }
    };

    // ---- bidding rounds (rbase carries tie-rotation parity across calls) ----
    auto runRounds = [&](int nrounds, int rbase) {
        for (int round = 0; round < nrounds; ++round) {
            int nq = buildQueue();
            if (nq == 0) break;

            for (int q = wv; q < nq; q += 16) {
                int i = qbuf[q];
                float red[16];
                rowRed16(i, red);
                if (q + 16 < nq) prefRow(qbuf[q + 16]);
                // local (min, secmin, argmin-col 0-idx): 4 chains of depth 4
                float a1 = INFV, a2 = INFV; int ac = 0;
                float e1 = INFV, e2 = INFV; int ec = 0;
                float f1 = INFV, f2 = INFV; int fc = 0;
                float g1 = INFV, g2 = INFV; int gc = 0;
#pragma unroll
                for (int k = 0; k < 4; ++k) {
                    float u0 = red[k];
                    bool t0 = u0 < a1;
                    a2 = t0 ? a1 : (u0 < a2 ? u0 : a2);
                    ac = t0 ? (lane * 16 + k) : ac;  a1 = t0 ? u0 : a1;
                    float u1 = red[k + 4];
                    bool t1 = u1 < e1;
                    e2 = t1 ? e1 : (u1 < e2 ? u1 : e2);
                    ec = t1 ? (lane * 16 + k + 4) : ec;  e1 = t1 ? u1 : e1;
                    float u2 = red[k + 8];
                    bool t2 = u2 < f1;
                    f2 = t2 ? f1 : (u2 < f2 ? u2 : f2);
                    fc = t2 ? (lane * 16 + k + 8) : fc;  f1 = t2 ? u2 : f1;
                    float u3 = red[k + 12];
                    bool t3 = u3 < g1;
                    g2 = t3 ? g1 : (u3 < g2 ? u3 : g2);
                    gc = t3 ? (lane * 16 + k + 12) : gc;  g1 = t3 ? u3 : g1;
                }
                bool sae = e1 < a1;
                float ae1 = sae ? e1 : a1; int aec = sae ? ec : ac;
                float ae2 = fminf(fminf(a2, e2), sae ? a1 : e1);
                bool sfg = g1 < f1;
                float fg1 = sfg ? g1 : f1; int fgc = sfg ? gc : fc;
                float fg2 = fminf(fminf(f2, g2), sfg ? f1 : g1);
                bool sall = fg1 < ae1;
                float m1 = sall ? fg1 : ae1;
                int   c1 = sall ? fgc : aec;
                float m2 = fminf(fminf(ae2, fg2), sall ? ae1 : fg1);

                // wave argmin with payload (uniform results on all lanes)
                float gm1 = wave_min_f32(m1);
                unsigned long long wbm = __ballot(m1 == gm1);
                int wl = __ffsll((long long)wbm) - 1;
                float cand2 = (lane == wl) ? m2 : m1;
                float gm2 = wave_min_f32(cand2);
                int gcol;
                if (gm1 < gm2) {
                    gcol = __builtin_amdgcn_readlane(c1, wl);  // unique argmin
                } else {
                    // ties: prefer a FREE tied column; else rotate the
                    // occupied pick (lowest/highest by parity).
                    unsigned tmask = 0u;
#pragma unroll
                    for (int k = 0; k < 16; ++k)
                        tmask |= (red[k] == gm1) ? (1u << k) : 0u;
                    unsigned fmask = 0u;
                    unsigned tt = tmask;
                    while (tt) {
                        int k = __ffs((int)tt) - 1;
                        tt &= tt - 1;
                        if (colm[lane * 16 + k + 1] == 0) fmask |= (1u << k);
                    }
                    unsigned long long bf = __ballot(fmask != 0u);
                    if (bf != 0ull) {
                        int l = __ffsll((long long)bf) - 1;
                        unsigned mk = (unsigned)__builtin_amdgcn_readlane((int)fmask, l);
                        gcol = l * 16 + (__ffs((int)mk) - 1);
                    } else if ((rbase + round) & 1) {
                        unsigned long long ba = __ballot(tmask != 0u);
                        int l = 63 - __clzll(ba);               // highest lane
                        unsigned mk = (unsigned)__builtin_amdgcn_readlane((int)tmask, l);
                        gcol = l * 16 + (31 - __clz((int)mk));  // highest col
                    } else {
                        gcol = __builtin_amdgcn_readlane(c1, wl); // lowest col
                    }
                }
                float inc = gm2 - gm1;                          // >= 0

                if (lane == 0) {
                    unsigned long long key =
                        ((unsigned long long)__float_as_uint(inc) << 32) |
                        (unsigned long long)(unsigned)i;
                    atomicMax(&bid[gcol + 1], key);
                }
            }
            __syncthreads();

            // acceptance: column j takes its best bid; displaced row freed
            for (int j = tid + 1; j <= N; j += 1024) {
                unsigned long long bb = bid[j];
                if (bb != 0ull) {
                    bid[j] = 0ull;
                    int i = (int)(unsigned)(bb & 0xFFFFFFFFull);
                    float inc = __uint_as_float((unsigned)(bb >> 32));
                    int old = colm[j];
                    colm[j] = i;
                    rowm[i] = j;
                    if (old) rowm[old] = 0;
                    v0T[((j - 1) & 15) * 64 + ((j - 1) >> 4)] -= inc;
                }
            }
            __syncthreads();
        }
    };

    // drop any non-tight match (red != rowmin), freeing it to re-bid
    auto midFixup = [&]() {
        for (int q = wv; q < N; q += 16) {
            int i = q + 1;
            if (i + 16 <= N) prefRow(i + 16);   // flies under this row's work
            int j = rowm[i];                // wave-uniform (LDS broadcast)
            if (j == 0) continue;
            float red[16];
            rowRed16(i, red);
            int lo = (j - 1) >> 4, kk = (j - 1) & 15;
            float rloc = red[0];
#pragma unroll
            for (int k = 1; k < 16; ++k) if (k == kk) rloc = red[k];
#pragma unroll
            for (int s = 1; s < 16; s <<= 1) {
#pragma unroll
                for (int k = 0; k < 16; k += 2 * s)
                    red[k] = fminf(red[k], red[k + s]);
            }
            float m = wave_min_f32(red[0]);
            float rm = __int_as_float(
                __builtin_amdgcn_readlane(__float_as_int(rloc), lo));
            if (lane == 0 && rm != m) { rowm[i] = 0; colm[j] = 0; }
        }
    };

    // ---- phase schedule: 32 rounds, then 20 x {fixup; conv-exit?; 12} ----
    runRounds(AUC_R1, 0);
    for (int ph = 0; ph < AUC_PHASES; ++ph) {
        midFixup();
        __syncthreads();
        // convergence exit: ballot count of free rows (no atomics)
        {
            int i = tid + 1;
            bool fr = (rowm[i] == 0);
            unsigned long long mb = __ballot(fr);
            if (lane == 0) wcnt[wv] = __popcll(mb);
            __syncthreads();
            int nfree = 0;
#pragma unroll
            for (int w = 0; w < 16; ++w) nfree += wcnt[w];
            __syncthreads();
            if (nfree == 0) break;
        }
        runRounds(AUC_RP, ph);
    }

    // ---- final u-fixup: u_i = rowmin(red_i); drop non-tight ----
    for (int q = wv; q < N; q += 16) {
        int i = q + 1;
        if (i + 16 <= N) prefRow(i + 16);
        float red[16];
        rowRed16(i, red);
        int j = rowm[i];                    // wave-uniform (LDS broadcast)
        float rloc = red[0];
        int lo = 0, kk = 0;
        if (j) {
            lo = (j - 1) >> 4; kk = (j - 1) & 15;
#pragma unroll
            for (int k = 1; k < 16; ++k) if (k == kk) rloc = red[k];
        }
#pragma unroll
        for (int s = 1; s < 16; s <<= 1) {
#pragma unroll
            for (int k = 0; k < 16; k += 2 * s)
                red[k] = fminf(red[k], red[k + s]);
        }
        float m = wave_min_f32(red[0]);
        if (j) {
            float rm = __int_as_float(
                __builtin_amdgcn_readlane(__float_as_int(rloc), lo));
            if (lane == 0 && rm != m) { rowm[i] = 0; colm[j] = 0; }
        }
        if (lane == 0) Uw[b * N + q] = m;
    }
    __syncthreads();

    // ---- write state for the SSP kernel ----
    for (int c = tid; c < N; c += 1024) {
        Vw[b * N + c] = v0T[(c & 15) * 64 + (c >> 4)];
        Cw[b * N + c] = colm[c + 1];
    }
    for (int t = tid; t < N; t += 1024) Rw[b * N + t] = rowm[t + 1];
}

struct Frag { uint4 w0, w1; float ur; float4 q; };

template<bool CACHED, bool PRE>
__global__ __launch_bounds__(64, 1)
void emd_jv_kernel(const float* __restrict__ S1,
                   const float* __restrict__ S2,
                   const __half* __restrict__ Dc,
                   const float* __restrict__ Vin,
                   const int*   __restrict__ Iin,
                   const float* __restrict__ Uw,
                   const int*   __restrict__ Cw,
                   const int*   __restrict__ Rw,
                   float* __restrict__ out) {
    __shared__ float4 s1u[N + 1];     // row coords (both modes; final fp32 sum)
    __shared__ float  u_lds[N + 1];   // row potentials
    __shared__ float  dentry[N + 1];  // D value when column settled
    __shared__ int    rowm[N + 1];    // row -> matched col (0 = free)

    const int lane = threadIdx.x;
    const int b = blockIdx.x;
    const float* s1g = S1 + (size_t)b * N * 3;
    const float* s2g = S2 + (size_t)b * N * 3;
    const __half* Db = CACHED ? (Dc + ((size_t)b << 20)) : (const __half*)0;
    const float NANF = __int_as_float(0x7fc00000);

    for (int t = lane; t < N; t += 64) {
        s1u[t + 1] = make_float4(s1g[3 * t], s1g[3 * t + 1], s1g[3 * t + 2], 0.0f);
        u_lds[t + 1] = PRE ? Uw[b * N + t] : 0.0f;
        rowm[t + 1] = PRE ? Rw[b * N + t] : 0;
    }
    if (lane == 0) { u_lds[0] = 0.0f; rowm[0] = 0; }

    // ---- per-lane column state: col j = c+1, c = lane*16+k ----
    float v[NSLOT];       // column potentials
    int   pr[NSLOT];      // matched row (0 = free)
    int   jpk[NSLOT];     // packed (pr<<11)|j
    float x2[NSLOT], y2[NSLOT], z2[NSLOT];  // S2 coords (final fp32 sum)

#pragma unroll
    for (int k = 0; k < NSLOT; ++k) {
        int pt = lane * NSLOT + k;
        x2[k] = s2g[3 * pt + 0];
        y2[k] = s2g[3 * pt + 1];
        z2[k] = s2g[3 * pt + 2];
    }

    if constexpr (PRE) {
#pragma unroll
        for (int k = 0; k < NSLOT; ++k) {
            int c = lane * NSLOT + k;
            v[k] = Vin[b * N + c];        // Vin = auction-updated v
            pr[k] = Cw[b * N + c];
            jpk[k] = (pr[k] << 11) | (c + 1);
        }
        __syncthreads();
    } else {
        int imin[NSLOT];
        if constexpr (CACHED) {
#pragma unroll
            for (int k = 0; k < NSLOT; ++k) {
                int c = lane * NSLOT + k;
                v[k] = Vin[b * N + c];
                imin[k] = Iin[b * N + c];
            }
        } else {
#pragma unroll
            for (int k = 0; k < NSLOT; ++k) { v[k] = INFV; imin[k] = 1; }
        }
        __syncthreads();

        if constexpr (!CACHED) {
            for (int r = 1; r <= N; ++r) {
                float4 qq = s1u[r];
#pragma unroll
                for (int k = 0; k < NSLOT; ++k) {
                    float dx = qq.x - x2[k], dy = qq.y - y2[k], dz = qq.z - z2[k];
                    float d2 = dx * dx + dy * dy + dz * dz;
                    bool upd = d2 < v[k];
                    v[k] = upd ? d2 : v[k];
                    imin[k] = upd ? r : imin[k];
                }
            }
#pragma unroll
            for (int k = 0; k < NSLOT; ++k) v[k] = sqrtf(v[k]);
        }

        // greedy matching on tight edges
#pragma unroll
        for (int k = 0; k < NSLOT; ++k) {
            int j = lane * NSLOT + k + 1;
            int r = imin[k];
            int old = atomicCAS(&rowm[r], 0, j);
            pr[k] = (old == 0) ? r : 0;
            jpk[k] = (pr[k] << 11) | j;
        }
        __syncthreads();
    }

    float minv[NSLOT];
    int   way[NSLOT];

    // issue row-r loads (cost-row fragment + u[r]); consumer waits only these
    auto issueLoads = [&](int rr) -> Frag {
        Frag F;
        if (CACHED) {
            const uint4* dr = (const uint4*)(Db + (size_t)(rr - 1) * N);
            F.w0 = dr[lane * 2 + 0];       // 8 halves
            F.w1 = dr[lane * 2 + 1];       // 8 halves
        } else {
            F.q = s1u[rr];
        }
        F.ur = u_lds[rr];
        return F;
    };

    auto applyFrag = [&](const Frag& F, int jpred, float Dh) {
        float base = Dh - F.ur;
        if (CACHED) {
            float h[NSLOT];
            const unsigned* w = (const unsigned*)&F.w0;   // w0,w1 contiguous
#pragma unroll
            for (int t = 0; t < 8; ++t) {
                unsigned word = w[t];
                __half2 hh = *reinterpret_cast<const __half2*>(&word);
                float2 f2 = __half22float2(hh);
                h[2 * t] = f2.x; h[2 * t + 1] = f2.y;
            }
#pragma unroll
            for (int k = 0; k < NSLOT; ++k) {
                float cur = (h[k] - v[k]) + base;
                bool upd = cur < minv[k];         // false for NaN (settled)
                minv[k] = upd ? cur : minv[k];
                way[k] = upd ? jpred : way[k];
            }
        } else {
#pragma unroll
            for (int k = 0; k < NSLOT; ++k) {
                float dx = F.q.x - x2[k], dy = F.q.y - y2[k], dz = F.q.z - z2[k];
                float d = sqrtf(dx * dx + dy * dy + dz * dz);
                float cur = (d - v[k]) + base;
                bool upd = cur < minv[k];
                minv[k] = upd ? cur : minv[k];
                way[k] = upd ? jpred : way[k];
            }
        }
    };

    // ---- successive shortest paths for free rows (exact on C') ----
    for (int i = 1; i <= N; ++i) {
        if (rowm[i] != 0) continue;

        unsigned used = 0u;
        float DT = 0.0f;
        int freecol = 0;
        int pred = 0;      // speculative prefetch: predicted next winner row
        Frag P;            // only read when pred != 0 (assigned then)

        Frag F0 = issueLoads(i);          // overlaps minv/way init
#pragma unroll
        for (int k = 0; k < NSLOT; ++k) { minv[k] = INFV; way[k] = 0; }
        applyFrag(F0, 0, 0.0f);

        int guard = 0;
        for (;;) {
            if (++guard > N + 4) break;
            // local argmin: 4 independent depth-4 chains + 2-level merge.
            float b0 = INFV, b1 = INFV, b2 = INFV, b3 = INFV;
            int   p0 = 0, p1 = 0, p2 = 0, p3 = 0;
#pragma unroll
            for (int k = 0; k < 4; ++k) {
                bool t0 = minv[k]      < b0;
                b0 = t0 ? minv[k]      : b0;  p0 = t0 ? jpk[k]      : p0;
                bool t1 = minv[k + 4]  < b1;
                b1 = t1 ? minv[k + 4]  : b1;  p1 = t1 ? jpk[k + 4]  : p1;
                bool t2 = minv[k + 8]  < b2;
                b2 = t2 ? minv[k + 8]  : b2;  p2 = t2 ? jpk[k + 8]  : p2;
                bool t3 = minv[k + 12] < b3;
                b3 = t3 ? minv[k + 12] : b3;  p3 = t3 ? jpk[k + 12] : p3;
            }
            bool m01 = b1 < b0;  float ba = m01 ? b1 : b0;  int pa = m01 ? p1 : p0;
            bool m23 = b3 < b2;  float bb = m23 ? b3 : b2;  int pb = m23 ? p3 : p2;
            bool mab = bb < ba;  float bestv = mab ? bb : ba;
            int bestjp = mab ? pb : pa;

            float gmin = wave_min_f32(bestv);
            if (!(gmin < INFV * 0.5f)) break;
            unsigned long long tm = __ballot(bestv == gmin);
            DT = gmin;
            freecol = 0;

            // 1) free-column short-circuit: single ballot (equivalent to
            //    scanning ties lowest-lane-first for a free bestjp)
            {
                unsigned long long tf =
                    __ballot((bestv == gmin) && ((bestjp >> 11) == 0));
                if (tf) {
                    int l = __ffsll((long long)tf) - 1;
                    freecol = __builtin_amdgcn_readlane(bestjp, l) & 0x7FF;
                }
            }
            if (freecol) break;

            // 2) settle all matched ties at gmin
            bool first = true;
            while (tm) {
                int l = __ffsll((long long)tm) - 1;
                tm &= tm - 1;
                int jp = __builtin_amdgcn_readlane(bestjp, l);
                int jj = jp & 0x7FF, rr = jp >> 11;
                Frag F;
                if (CACHED && first && pred != 0 && rr == pred) {
                    F = P;                         // prefetch hit: data resident
                } else {
                    F = issueLoads(rr);            // loads fly during marking
                }
                if (CACHED && first) {
                    // runner-up prefetch for the NEXT round; the wave-min +
                    // ballot here hides under the winner's L2 load latency.
                    float ru = (bestv == gmin) ? INFV : bestv;
                    float rmin = wave_min_f32(ru);
                    pred = 0;
                    if (rmin < INFV * 0.5f) {
                        unsigned long long rb = __ballot(ru == rmin);
                        int rl = __ffsll((long long)rb) - 1;
                        int rjp = __builtin_amdgcn_readlane(bestjp, rl);
                        int prr = rjp >> 11;
                        if (prr != 0) { pred = prr; P = issueLoads(prr); }
                    }
                }
                first = false;
                if (lane == 0) dentry[jj] = gmin;
                int cc = jj - 1, lo = cc >> 4, kk = cc & 15;
                bool mine = (lane == lo);
#pragma unroll
                for (int k = 0; k < NSLOT; ++k)
                    if (k == kk && mine) { minv[k] = NANF; used |= (1u << k); }
                applyFrag(F, jj, gmin);
            }
        }
        if (freecol == 0) continue;

        // deferred dual updates (pre-augment pr)
        if (lane == 0) u_lds[i] += DT;
#pragma unroll
        for (int k = 0; k < NSLOT; ++k) {
            if ((used >> k) & 1u) {
                int j = lane * NSLOT + k + 1;
                float dd = DT - dentry[j];
                v[k] -= dd;
                u_lds[pr[k]] += dd;      // distinct rows: race-free
            }
        }
        __syncthreads();

        // augment along alternating path (register p via readlanes)
        int j0 = freecol;
        int aguard = 0;
        while (j0 != 0) {
            if (++aguard > N + 4) break;
            int cc = j0 - 1;
            int lo = cc >> 4, kk = cc & 15;
            int wloc = way[0];
#pragma unroll
            for (int k = 1; k < NSLOT; ++k) if (k == kk) wloc = way[k];
            int j1 = __builtin_amdgcn_readlane(wloc, lo);
            int np;
            if (j1 == 0) np = i;
            else {
                int c1 = j1 - 1;
                int lo1 = c1 >> 4, kk1 = c1 & 15;
                int ploc = pr[0];
#pragma unroll
                for (int k = 1; k < NSLOT; ++k) if (k == kk1) ploc = pr[k];
                np = __builtin_amdgcn_readlane(ploc, lo1);
            }
            bool mine = (lane == lo);
#pragma unroll
            for (int k = 0; k < NSLOT; ++k)
                if (k == kk) {
                    if (mine) { pr[k] = np; jpk[k] = (np << 11) | j0; }
                }
            if (lane == 0) rowm[np] = j0;
            j0 = j1;
        }
        __syncthreads();
    }

    // ---- total matched cost: exact fp32 from coordinates ----
    float sum = 0.0f;
#pragma unroll
    for (int k = 0; k < NSLOT; ++k) {
        int r = pr[k] > 0 ? pr[k] : 1;
        float4 qq = s1u[r];
        float dx = qq.x - x2[k], dy = qq.y - y2[k], dz = qq.z - z2[k];
        sum += sqrtf(dx * dx + dy * dy + dz * dz);
    }
#pragma unroll
    for (int off = 32; off >= 1; off >>= 1) sum += __shfl_xor(sum, off);
    if (lane == 0) atomicAdd(out, sum * (1.0f / ((float)N * (float)BATCH)));
}

extern "C" void kernel_launch(void* const* d_in, const int* in_sizes, int n_in,
                              void* d_out, int out_size, void* d_ws, size_t ws_size,
                              hipStream_t stream) {
    const float* S1 = (const float*)d_in[0];
    const float* S2 = (const float*)d_in[1];
    float* out = (float*)d_out;

    size_t needD  = (size_t)BATCH * N * N * sizeof(__half);
    size_t vecB   = (size_t)BATCH * N * 4;            // one per-col/per-row array
    size_t needT  = needD + 2 * vecB;                 // V + I            (R8 tier)
    size_t needT2 = needD + 6 * vecB;                 // + Vw,Uw,Cw,Rw    (R13 tier)

    emd_zero_kernel<<<1, 1, 0, stream>>>(out);

    if (ws_size >= needT2) {
        __half* D  = (__half*)d_ws;
        float*  V  = (float*)((char*)d_ws + needD);
        int*    I  = (int*)((char*)V + vecB);
        float*  Vw = (float*)((char*)I + vecB);
        float*  Uw = (float*)((char*)Vw + vecB);
        int*    Cw = (int*)((char*)Uw + vecB);
        int*    Rw = (int*)((char*)Cw + vecB);
        emd_dist_kernel<<<BATCH * N, 256, 0, stream>>>(S1, S2, D);
        emd_colmin_kernel<<<BATCH * 4, 256, 0, stream>>>(D, V, I);
        emd_auction_kernel<<<BATCH, 1024, 0, stream>>>(D, V, I, Vw, Uw, Cw, Rw);
        emd_jv_kernel<true, true><<<BATCH, 64, 0, stream>>>(
            S1, S2, D, Vw, nullptr, Uw, Cw, Rw, out);
    } else if (ws_size >= needT) {
        __half* D = (__half*)d_ws;
        float*  V = (float*)((char*)d_ws + needD);
        int*    I = (int*)((char*)V + vecB);
        emd_dist_kernel<<<BATCH * N, 256, 0, stream>>>(S1, S2, D);
        emd_colmin_kernel<<<BATCH * 4, 256, 0, stream>>>(D, V, I);
        emd_jv_kernel<true, false><<<BATCH, 64, 0, stream>>>(
            S1, S2, D, V, I, nullptr, nullptr, nullptr, out);
    } else {
        emd_jv_kernel<false, false><<<BATCH, 64, 0, stream>>>(
            S1, S2, nullptr, nullptr, nullptr, nullptr, nullptr, nullptr, out);
    }
}

// Round 19
// 15369.832 us; speedup vs baseline: 1.0812x; 1.0135x over previous
//
#include <hip/hip_runtime.h>
#include <hip/hip_fp16.h>
#include <math.h>

// EarthMoverDistance: exact Hungarian (JV successive shortest path).
// B=8, N=1024, 3-D Euclidean cost. SSP: one wave per batch; lane owns 16
// columns (c = lane*16+k) in registers.
// R25 (= R24 with AUC_PHASES 20 -> 12; single-variable):
//  - R24 post-mortem: ballot queue compaction was NEUTRAL (auction still
//    ~2.2ms) => cost is in the bid scans themselves (tie ping-pong keeps
//    qn high through all rounds). Phase count trades jv<->auction ~1:1:
//    12ph = 13.7 jv + 1.35 auc (R20, conflicted reads); 20ph = 13.0 +
//    2.2 (R21/R24, transposed reads). The unmeasured cell: 12 phases
//    WITH the transpose (per-round cost reducer, bit-state-neutral).
//    Expect auction ~1.0-1.2 at R20's jv tradeoff point (~13.6-13.7).
//  - If total lands >= 15.4: the phase/cost curve is flat within noise
//    everywhere measured; config family exhausted (latency-bound serial
//    SSP at 0.27% VALUBusy, not a HW roofline).
//  Correctness unconditional (R16-R24): prices only decrease => red >= 0;
//  final u-fixup enforces red == rowmin on kept matches; SSP exact.
// fp16 cost matrix in d_ws (2 MB/batch, XCD-L2 resident); FINAL SUM
// recomputed in fp32 from coords (absmax 0.0 across R6-R24 variants).

#define N     1024
#define BATCH 8
#define NSLOT 16          // columns per lane (SSP)
#define INFV  1e9f
#define AUC_R1 32         // initial bidding rounds
#define AUC_RP 12         // rounds per drop-rebid phase
#define AUC_PHASES 12     // drop-rebid phases (convergence exit only)

__global__ void emd_zero_kernel(float* out) { out[0] = 0.0f; }

// ---- cost cache: D[b][r][c] = fp16(dist(S1[b][r], S2[b][c])) ----
__global__ __launch_bounds__(256)
void emd_dist_kernel(const float* __restrict__ S1, const float* __restrict__ S2,
                     __half* __restrict__ D) {
    int b = blockIdx.x >> 10;
    int r = blockIdx.x & (N - 1);
    const float* s1 = S1 + ((size_t)b * N + r) * 3;
    float x1 = s1[0], y1 = s1[1], z1 = s1[2];
    const float* s2 = S2 + (size_t)b * N * 3;
    __half* drow = D + ((size_t)b * N + r) * (size_t)N;
    for (int c = threadIdx.x; c < N; c += 256) {
        float dx = x1 - s2[3 * c], dy = y1 - s2[3 * c + 1], dz = z1 - s2[3 * c + 2];
        drow[c] = __float2half_rn(sqrtf(dx * dx + dy * dy + dz * dz));
    }
}

// ---- column reduction over the fp16 matrix: v[c] = min_r C'(r,c) ----
__global__ __launch_bounds__(256)
void emd_colmin_kernel(const __half* __restrict__ D, float* __restrict__ V,
                       int* __restrict__ I) {
    int b = blockIdx.x >> 2;
    int c = ((blockIdx.x & 3) << 8) + threadIdx.x;
    const __half* Db = D + ((size_t)b << 20);
    float best = INFV; int bi = 1;
    for (int r = 0; r < N; ++r) {
        float d = __half2float(Db[(size_t)r * N + c]);
        if (d < best) { best = d; bi = r + 1; }
    }
    V[b * N + c] = best;
    I[b * N + c] = bi;
}

template<int CTRL>
__device__ __forceinline__ float dppmin(float x) {
    int xi = __float_as_int(x);
    int yi = __builtin_amdgcn_update_dpp(xi, xi, CTRL, 0xF, 0xF, false);
    return fminf(x, __int_as_float(yi));
}

__device__ __forceinline__ float wave_min_f32(float x) {
    x = dppmin<0x111>(x);   // row_shr:1
    x = dppmin<0x112>(x);   // row_shr:2
    x = dppmin<0x114>(x);   // row_shr:4
    x = dppmin<0x118>(x);   // row_shr:8
    x = dppmin<0x142>(x);   // row_bcast:15
    x = dppmin<0x143>(x);   // row_bcast:31 -> lane 63 has global min
    return __int_as_float(__builtin_amdgcn_readlane(__float_as_int(x), 63));
}

// ---- parallel auction initializer: 1024 threads (16 waves) per batch ----
// Invariants on exit (enforced by final u-fixup): red(i,j)=C'(i,j)-u_i-v_j
// >= 0 for all i,j (u_i = rowmin); red == 0 on every kept match.
// v stored TRANSPOSED in LDS: v0T[k*64 + lane] = v[lane*16 + k].
__global__ __launch_bounds__(1024, 1)
void emd_auction_kernel(const __half* __restrict__ Dc,
                        const float* __restrict__ Vin,
                        const int* __restrict__ Iin,
                        float* __restrict__ Vw, float* __restrict__ Uw,
                        int* __restrict__ Cw, int* __restrict__ Rw) {
    __shared__ float v0T[N];                // column potentials, TRANSPOSED
    __shared__ int   rowm[N + 1];           // row -> col (1-idx), 0 = free
    __shared__ int   colm[N + 1];           // col -> row (1-idx), 0 = free
    __shared__ unsigned long long bid[N + 1];
    __shared__ int   qbuf[N];
    __shared__ int   wcnt[16];              // per-wave free counts (compaction)

    const int tid  = threadIdx.x;
    const int lane = tid & 63;
    const int wv   = tid >> 6;              // wave id 0..15
    const int b    = blockIdx.x;
    const __half* Db = Dc + ((size_t)b << 20);

    for (int t = tid; t <= N; t += 1024) { rowm[t] = 0; colm[t] = 0; bid[t] = 0ull; }
    for (int c = tid; c < N; c += 1024)
        v0T[(c & 15) * 64 + (c >> 4)] = Vin[b * N + c];
    __syncthreads();

    // greedy on tight edges (column -> its argmin row from colmin kernel)
    for (int c = tid; c < N; c += 1024) {
        int r = Iin[b * N + c];             // 1-indexed row
        int old = atomicCAS(&rowm[r], 0, c + 1);
        if (old == 0) colm[c + 1] = r;
    }
    __syncthreads();

    // ballot-based free-row queue build: each thread owns row tid+1.
    // Returns nq (uniform); fills qbuf[0..nq). Outcome-neutral vs the
    // old atomicAdd build. Barriers uniform: all threads call.
    auto buildQueue = [&]() -> int {
        int i = tid + 1;
        bool fr = (rowm[i] == 0);
        unsigned long long mb = __ballot(fr);
        int pre = __popcll(mb & ((1ull << lane) - 1ull));
        if (lane == 0) wcnt[wv] = __popcll(mb);
        __syncthreads();
        int base = 0, nq = 0;
#pragma unroll
        for (int w = 0; w < 16; ++w) {
            int c = wcnt[w];
            base += (w < wv) ? c : 0;
            nq += c;
        }
        if (fr) qbuf[base + pre] = i;
        __syncthreads();
        return nq;
    };

    // ---- raw next-row prefetch cache (cost matrix constant, never stale) ----
    uint4 pw0, pw1; int pi = 0;
    auto prefRow = [&](int rr) {
        const uint4* dr = (const uint4*)(Db + (size_t)(rr - 1) * N);
        pw0 = dr[lane * 2 + 0];
        pw1 = dr[lane * 2 + 1];
        pi = rr;
    };
    // red[k] = C'(i, lane*16+k) - v[lane*16+k]; conflict-free transposed v.
    auto rowRed16 = [&](int i, float (&red)[16]) {
        uint4 w0, w1;
        if (i == pi) { w0 = pw0; w1 = pw1; }
        else {
            const uint4* dr = (const uint4*)(Db + (size_t)(i - 1) * N);
            w0 = dr[lane * 2 + 0];
            w1 = dr[lane * 2 + 1];
        }
        unsigned wb[8] = { w0.x, w0.y, w0.z, w0.w, w1.x, w1.y, w1.z, w1.w };
#pragma unroll
        for (int t = 0; t < 8; ++t) {
            __half2 hh = *reinterpret_cast<const __half2*>(&wb[t]);
            float2 f2 = __half22float2(hh);
            red[2 * t]     = f2.x - v0T[(2 * t) * 64 + lane];
            red[2 * t + 1] = f2.y - v0T[(2 * t + 1) * 64 + lane];
        }
    };

    // ---- bidding rounds (rbase carries tie-rotation parity across calls) ----
    auto runRounds = [&](int nrounds, int rbase) {
        for (int round = 0; round < nrounds; ++round) {
            int nq = buildQueue();
            if (nq == 0) break;

            for (int q = wv; q < nq; q += 16) {
                int i = qbuf[q];
                float red[16];
                rowRed16(i, red);
                if (q + 16 < nq) prefRow(qbuf[q + 16]);
                // local (min, secmin, argmin-col 0-idx): 4 chains of depth 4
                float a1 = INFV, a2 = INFV; int ac = 0;
                float e1 = INFV, e2 = INFV; int ec = 0;
                float f1 = INFV, f2 = INFV; int fc = 0;
                float g1 = INFV, g2 = INFV; int gc = 0;
#pragma unroll
                for (int k = 0; k < 4; ++k) {
                    float u0 = red[k];
                    bool t0 = u0 < a1;
                    a2 = t0 ? a1 : (u0 < a2 ? u0 : a2);
                    ac = t0 ? (lane * 16 + k) : ac;  a1 = t0 ? u0 : a1;
                    float u1 = red[k + 4];
                    bool t1 = u1 < e1;
                    e2 = t1 ? e1 : (u1 < e2 ? u1 : e2);
                    ec = t1 ? (lane * 16 + k + 4) : ec;  e1 = t1 ? u1 : e1;
                    float u2 = red[k + 8];
                    bool t2 = u2 < f1;
                    f2 = t2 ? f1 : (u2 < f2 ? u2 : f2);
                    fc = t2 ? (lane * 16 + k + 8) : fc;  f1 = t2 ? u2 : f1;
                    float u3 = red[k + 12];
                    bool t3 = u3 < g1;
                    g2 = t3 ? g1 : (u3 < g2 ? u3 : g2);
                    gc = t3 ? (lane * 16 + k + 12) : gc;  g1 = t3 ? u3 : g1;
                }
                bool sae = e1 < a1;
                float ae1 = sae ? e1 : a1; int aec = sae ? ec : ac;
                float ae2 = fminf(fminf(a2, e2), sae ? a1 : e1);
                bool sfg = g1 < f1;
                float fg1 = sfg ? g1 : f1; int fgc = sfg ? gc : fc;
                float fg2 = fminf(fminf(f2, g2), sfg ? f1 : g1);
                bool sall = fg1 < ae1;
                float m1 = sall ? fg1 : ae1;
                int   c1 = sall ? fgc : aec;
                float m2 = fminf(fminf(ae2, fg2), sall ? ae1 : fg1);

                // wave argmin with payload (uniform results on all lanes)
                float gm1 = wave_min_f32(m1);
                unsigned long long wbm = __ballot(m1 == gm1);
                int wl = __ffsll((long long)wbm) - 1;
                float cand2 = (lane == wl) ? m2 : m1;
                float gm2 = wave_min_f32(cand2);
                int gcol;
                if (gm1 < gm2) {
                    gcol = __builtin_amdgcn_readlane(c1, wl);  // unique argmin
                } else {
                    // ties: prefer a FREE tied column; else rotate the
                    // occupied pick (lowest/highest by parity).
                    unsigned tmask = 0u;
#pragma unroll
                    for (int k = 0; k < 16; ++k)
                        tmask |= (red[k] == gm1) ? (1u << k) : 0u;
                    unsigned fmask = 0u;
                    unsigned tt = tmask;
                    while (tt) {
                        int k = __ffs((int)tt) - 1;
                        tt &= tt - 1;
                        if (colm[lane * 16 + k + 1] == 0) fmask |= (1u << k);
                    }
                    unsigned long long bf = __ballot(fmask != 0u);
                    if (bf != 0ull) {
                        int l = __ffsll((long long)bf) - 1;
                        unsigned mk = (unsigned)__builtin_amdgcn_readlane((int)fmask, l);
                        gcol = l * 16 + (__ffs((int)mk) - 1);
                    } else if ((rbase + round) & 1) {
                        unsigned long long ba = __ballot(tmask != 0u);
                        int l = 63 - __clzll(ba);               // highest lane
                        unsigned mk = (unsigned)__builtin_amdgcn_readlane((int)tmask, l);
                        gcol = l * 16 + (31 - __clz((int)mk));  // highest col
                    } else {
                        gcol = __builtin_amdgcn_readlane(c1, wl); // lowest col
                    }
                }
                float inc = gm2 - gm1;                          // >= 0

                if (lane == 0) {
                    unsigned long long key =
                        ((unsigned long long)__float_as_uint(inc) << 32) |
                        (unsigned long long)(unsigned)i;
                    atomicMax(&bid[gcol + 1], key);
                }
            }
            __syncthreads();

            // acceptance: column j takes its best bid; displaced row freed
            for (int j = tid + 1; j <= N; j += 1024) {
                unsigned long long bb = bid[j];
                if (bb != 0ull) {
                    bid[j] = 0ull;
                    int i = (int)(unsigned)(bb & 0xFFFFFFFFull);
                    float inc = __uint_as_float((unsigned)(bb >> 32));
                    int old = colm[j];
                    colm[j] = i;
                    rowm[i] = j;
                    if (old) rowm[old] = 0;
                    v0T[((j - 1) & 15) * 64 + ((j - 1) >> 4)] -= inc;
                }
            }
            __syncthreads();
        }
    };

    // drop any non-tight match (red != rowmin), freeing it to re-bid
    auto midFixup = [&]() {
        for (int q = wv; q < N; q += 16) {
            int i = q + 1;
            if (i + 16 <= N) prefRow(i + 16);   // flies under this row's work
            int j = rowm[i];                // wave-uniform (LDS broadcast)
            if (j == 0) continue;
            float red[16];
            rowRed16(i, red);
            int lo = (j - 1) >> 4, kk = (j - 1) & 15;
            float rloc = red[0];
#pragma unroll
            for (int k = 1; k < 16; ++k) if (k == kk) rloc = red[k];
#pragma unroll
            for (int s = 1; s < 16; s <<= 1) {
#pragma unroll
                for (int k = 0; k < 16; k += 2 * s)
                    red[k] = fminf(red[k], red[k + s]);
            }
            float m = wave_min_f32(red[0]);
            float rm = __int_as_float(
                __builtin_amdgcn_readlane(__float_as_int(rloc), lo));
            if (lane == 0 && rm != m) { rowm[i] = 0; colm[j] = 0; }
        }
    };

    // ---- phase schedule: 32 rounds, then 12 x {fixup; conv-exit?; 12} ----
    runRounds(AUC_R1, 0);
    for (int ph = 0; ph < AUC_PHASES; ++ph) {
        midFixup();
        __syncthreads();
        // convergence exit: ballot count of free rows (no atomics)
        {
            int i = tid + 1;
            bool fr = (rowm[i] == 0);
            unsigned long long mb = __ballot(fr);
            if (lane == 0) wcnt[wv] = __popcll(mb);
            __syncthreads();
            int nfree = 0;
#pragma unroll
            for (int w = 0; w < 16; ++w) nfree += wcnt[w];
            __syncthreads();
            if (nfree == 0) break;
        }
        runRounds(AUC_RP, ph);
    }

    // ---- final u-fixup: u_i = rowmin(red_i); drop non-tight ----
    for (int q = wv; q < N; q += 16) {
        int i = q + 1;
        if (i + 16 <= N) prefRow(i + 16);
        float red[16];
        rowRed16(i, red);
        int j = rowm[i];                    // wave-uniform (LDS broadcast)
        float rloc = red[0];
        int lo = 0, kk = 0;
        if (j) {
            lo = (j - 1) >> 4; kk = (j - 1) & 15;
#pragma unroll
            for (int k = 1; k < 16; ++k) if (k == kk) rloc = red[k];
        }
#pragma unroll
        for (int s = 1; s < 16; s <<= 1) {
#pragma unroll
            for (int k = 0; k < 16; k += 2 * s)
                red[k] = fminf(red[k], red[k + s]);
        }
        float m = wave_min_f32(red[0]);
        if (j) {
            float rm = __int_as_float(
                __builtin_amdgcn_readlane(__float_as_int(rloc), lo));
            if (lane == 0 && rm != m) { rowm[i] = 0; colm[j] = 0; }
        }
        if (lane == 0) Uw[b * N + q] = m;
    }
    __syncthreads();

    // ---- write state for the SSP kernel ----
    for (int c = tid; c < N; c += 1024) {
        Vw[b * N + c] = v0T[(c & 15) * 64 + (c >> 4)];
        Cw[b * N + c] = colm[c + 1];
    }
    for (int t = tid; t < N; t += 1024) Rw[b * N + t] = rowm[t + 1];
}

struct Frag { uint4 w0, w1; float ur; float4 q; };

template<bool CACHED, bool PRE>
__global__ __launch_bounds__(64, 1)
void emd_jv_kernel(const float* __restrict__ S1,
                   const float* __restrict__ S2,
                   const __half* __restrict__ Dc,
                   const float* __restrict__ Vin,
                   const int*   __restrict__ Iin,
                   const float* __restrict__ Uw,
                   const int*   __restrict__ Cw,
                   const int*   __restrict__ Rw,
                   float* __restrict__ out) {
    __shared__ float4 s1u[N + 1];     // row coords (both modes; final fp32 sum)
    __shared__ float  u_lds[N + 1];   // row potentials
    __shared__ float  dentry[N + 1];  // D value when column settled
    __shared__ int    rowm[N + 1];    // row -> matched col (0 = free)

    const int lane = threadIdx.x;
    const int b = blockIdx.x;
    const float* s1g = S1 + (size_t)b * N * 3;
    const float* s2g = S2 + (size_t)b * N * 3;
    const __half* Db = CACHED ? (Dc + ((size_t)b << 20)) : (const __half*)0;
    const float NANF = __int_as_float(0x7fc00000);

    for (int t = lane; t < N; t += 64) {
        s1u[t + 1] = make_float4(s1g[3 * t], s1g[3 * t + 1], s1g[3 * t + 2], 0.0f);
        u_lds[t + 1] = PRE ? Uw[b * N + t] : 0.0f;
        rowm[t + 1] = PRE ? Rw[b * N + t] : 0;
    }
    if (lane == 0) { u_lds[0] = 0.0f; rowm[0] = 0; }

    // ---- per-lane column state: col j = c+1, c = lane*16+k ----
    float v[NSLOT];       // column potentials
    int   pr[NSLOT];      // matched row (0 = free)
    int   jpk[NSLOT];     // packed (pr<<11)|j
    float x2[NSLOT], y2[NSLOT], z2[NSLOT];  // S2 coords (final fp32 sum)

#pragma unroll
    for (int k = 0; k < NSLOT; ++k) {
        int pt = lane * NSLOT + k;
        x2[k] = s2g[3 * pt + 0];
        y2[k] = s2g[3 * pt + 1];
        z2[k] = s2g[3 * pt + 2];
    }

    if constexpr (PRE) {
#pragma unroll
        for (int k = 0; k < NSLOT; ++k) {
            int c = lane * NSLOT + k;
            v[k] = Vin[b * N + c];        // Vin = auction-updated v
            pr[k] = Cw[b * N + c];
            jpk[k] = (pr[k] << 11) | (c + 1);
        }
        __syncthreads();
    } else {
        int imin[NSLOT];
        if constexpr (CACHED) {
#pragma unroll
            for (int k = 0; k < NSLOT; ++k) {
                int c = lane * NSLOT + k;
                v[k] = Vin[b * N + c];
                imin[k] = Iin[b * N + c];
            }
        } else {
#pragma unroll
            for (int k = 0; k < NSLOT; ++k) { v[k] = INFV; imin[k] = 1; }
        }
        __syncthreads();

        if constexpr (!CACHED) {
            for (int r = 1; r <= N; ++r) {
                float4 qq = s1u[r];
#pragma unroll
                for (int k = 0; k < NSLOT; ++k) {
                    float dx = qq.x - x2[k], dy = qq.y - y2[k], dz = qq.z - z2[k];
                    float d2 = dx * dx + dy * dy + dz * dz;
                    bool upd = d2 < v[k];
                    v[k] = upd ? d2 : v[k];
                    imin[k] = upd ? r : imin[k];
                }
            }
#pragma unroll
            for (int k = 0; k < NSLOT; ++k) v[k] = sqrtf(v[k]);
        }

        // greedy matching on tight edges
#pragma unroll
        for (int k = 0; k < NSLOT; ++k) {
            int j = lane * NSLOT + k + 1;
            int r = imin[k];
            int old = atomicCAS(&rowm[r], 0, j);
            pr[k] = (old == 0) ? r : 0;
            jpk[k] = (pr[k] << 11) | j;
        }
        __syncthreads();
    }

    float minv[NSLOT];
    int   way[NSLOT];

    // issue row-r loads (cost-row fragment + u[r]); consumer waits only these
    auto issueLoads = [&](int rr) -> Frag {
        Frag F;
        if (CACHED) {
            const uint4* dr = (const uint4*)(Db + (size_t)(rr - 1) * N);
            F.w0 = dr[lane * 2 + 0];       // 8 halves
            F.w1 = dr[lane * 2 + 1];       // 8 halves
        } else {
            F.q = s1u[rr];
        }
        F.ur = u_lds[rr];
        return F;
    };

    auto applyFrag = [&](const Frag& F, int jpred, float Dh) {
        float base = Dh - F.ur;
        if (CACHED) {
            float h[NSLOT];
            const unsigned* w = (const unsigned*)&F.w0;   // w0,w1 contiguous
#pragma unroll
            for (int t = 0; t < 8; ++t) {
                unsigned word = w[t];
                __half2 hh = *reinterpret_cast<const __half2*>(&word);
                float2 f2 = __half22float2(hh);
                h[2 * t] = f2.x; h[2 * t + 1] = f2.y;
            }
#pragma unroll
            for (int k = 0; k < NSLOT; ++k) {
                float cur = (h[k] - v[k]) + base;
                bool upd = cur < minv[k];         // false for NaN (settled)
                minv[k] = upd ? cur : minv[k];
                way[k] = upd ? jpred : way[k];
            }
        } else {
#pragma unroll
            for (int k = 0; k < NSLOT; ++k) {
                float dx = F.q.x - x2[k], dy = F.q.y - y2[k], dz = F.q.z - z2[k];
                float d = sqrtf(dx * dx + dy * dy + dz * dz);
                float cur = (d - v[k]) + base;
                bool upd = cur < minv[k];
                minv[k] = upd ? cur : minv[k];
                way[k] = upd ? jpred : way[k];
            }
        }
    };

    // ---- successive shortest paths for free rows (exact on C') ----
    for (int i = 1; i <= N; ++i) {
        if (rowm[i] != 0) continue;

        unsigned used = 0u;
        float DT = 0.0f;
        int freecol = 0;
        int pred = 0;      // speculative prefetch: predicted next winner row
        Frag P;            // only read when pred != 0 (assigned then)

        Frag F0 = issueLoads(i);          // overlaps minv/way init
#pragma unroll
        for (int k = 0; k < NSLOT; ++k) { minv[k] = INFV; way[k] = 0; }
        applyFrag(F0, 0, 0.0f);

        int guard = 0;
        for (;;) {
            if (++guard > N + 4) break;
            // local argmin: 4 independent depth-4 chains + 2-level merge.
            float b0 = INFV, b1 = INFV, b2 = INFV, b3 = INFV;
            int   p0 = 0, p1 = 0, p2 = 0, p3 = 0;
#pragma unroll
            for (int k = 0; k < 4; ++k) {
                bool t0 = minv[k]      < b0;
                b0 = t0 ? minv[k]      : b0;  p0 = t0 ? jpk[k]      : p0;
                bool t1 = minv[k + 4]  < b1;
                b1 = t1 ? minv[k + 4]  : b1;  p1 = t1 ? jpk[k + 4]  : p1;
                bool t2 = minv[k + 8]  < b2;
                b2 = t2 ? minv[k + 8]  : b2;  p2 = t2 ? jpk[k + 8]  : p2;
                bool t3 = minv[k + 12] < b3;
                b3 = t3 ? minv[k + 12] : b3;  p3 = t3 ? jpk[k + 12] : p3;
            }
            bool m01 = b1 < b0;  float ba = m01 ? b1 : b0;  int pa = m01 ? p1 : p0;
            bool m23 = b3 < b2;  float bb = m23 ? b3 : b2;  int pb = m23 ? p3 : p2;
            bool mab = bb < ba;  float bestv = mab ? bb : ba;
            int bestjp = mab ? pb : pa;

            float gmin = wave_min_f32(bestv);
            if (!(gmin < INFV * 0.5f)) break;
            unsigned long long tm = __ballot(bestv == gmin);
            DT = gmin;
            freecol = 0;

            // 1) free-column short-circuit: single ballot (equivalent to
            //    scanning ties lowest-lane-first for a free bestjp)
            {
                unsigned long long tf =
                    __ballot((bestv == gmin) && ((bestjp >> 11) == 0));
                if (tf) {
                    int l = __ffsll((long long)tf) - 1;
                    freecol = __builtin_amdgcn_readlane(bestjp, l) & 0x7FF;
                }
            }
            if (freecol) break;

            // 2) settle all matched ties at gmin
            bool first = true;
            while (tm) {
                int l = __ffsll((long long)tm) - 1;
                tm &= tm - 1;
                int jp = __builtin_amdgcn_readlane(bestjp, l);
                int jj = jp & 0x7FF, rr = jp >> 11;
                Frag F;
                if (CACHED && first && pred != 0 && rr == pred) {
                    F = P;                         // prefetch hit: data resident
                } else {
                    F = issueLoads(rr);            // loads fly during marking
                }
                if (CACHED && first) {
                    // runner-up prefetch for the NEXT round; the wave-min +
                    // ballot here hides under the winner's L2 load latency.
                    float ru = (bestv == gmin) ? INFV : bestv;
                    float rmin = wave_min_f32(ru);
                    pred = 0;
                    if (rmin < INFV * 0.5f) {
                        unsigned long long rb = __ballot(ru == rmin);
                        int rl = __ffsll((long long)rb) - 1;
                        int rjp = __builtin_amdgcn_readlane(bestjp, rl);
                        int prr = rjp >> 11;
                        if (prr != 0) { pred = prr; P = issueLoads(prr); }
                    }
                }
                first = false;
                if (lane == 0) dentry[jj] = gmin;
                int cc = jj - 1, lo = cc >> 4, kk = cc & 15;
                bool mine = (lane == lo);
#pragma unroll
                for (int k = 0; k < NSLOT; ++k)
                    if (k == kk && mine) { minv[k] = NANF; used |= (1u << k); }
                applyFrag(F, jj, gmin);
            }
        }
        if (freecol == 0) continue;

        // deferred dual updates (pre-augment pr)
        if (lane == 0) u_lds[i] += DT;
#pragma unroll
        for (int k = 0; k < NSLOT; ++k) {
            if ((used >> k) & 1u) {
                int j = lane * NSLOT + k + 1;
                float dd = DT - dentry[j];
                v[k] -= dd;
                u_lds[pr[k]] += dd;      // distinct rows: race-free
            }
        }
        __syncthreads();

        // augment along alternating path (register p via readlanes)
        int j0 = freecol;
        int aguard = 0;
        while (j0 != 0) {
            if (++aguard > N + 4) break;
            int cc = j0 - 1;
            int lo = cc >> 4, kk = cc & 15;
            int wloc = way[0];
#pragma unroll
            for (int k = 1; k < NSLOT; ++k) if (k == kk) wloc = way[k];
            int j1 = __builtin_amdgcn_readlane(wloc, lo);
            int np;
            if (j1 == 0) np = i;
            else {
                int c1 = j1 - 1;
                int lo1 = c1 >> 4, kk1 = c1 & 15;
                int ploc = pr[0];
#pragma unroll
                for (int k = 1; k < NSLOT; ++k) if (k == kk1) ploc = pr[k];
                np = __builtin_amdgcn_readlane(ploc, lo1);
            }
            bool mine = (lane == lo);
#pragma unroll
            for (int k = 0; k < NSLOT; ++k)
                if (k == kk) {
                    if (mine) { pr[k] = np; jpk[k] = (np << 11) | j0; }
                }
            if (lane == 0) rowm[np] = j0;
            j0 = j1;
        }
        __syncthreads();
    }

    // ---- total matched cost: exact fp32 from coordinates ----
    float sum = 0.0f;
#pragma unroll
    for (int k = 0; k < NSLOT; ++k) {
        int r = pr[k] > 0 ? pr[k] : 1;
        float4 qq = s1u[r];
        float dx = qq.x - x2[k], dy = qq.y - y2[k], dz = qq.z - z2[k];
        sum += sqrtf(dx * dx + dy * dy + dz * dz);
    }
#pragma unroll
    for (int off = 32; off >= 1; off >>= 1) sum += __shfl_xor(sum, off);
    if (lane == 0) atomicAdd(out, sum * (1.0f / ((float)N * (float)BATCH)));
}

extern "C" void kernel_launch(void* const* d_in, const int* in_sizes, int n_in,
                              void* d_out, int out_size, void* d_ws, size_t ws_size,
                              hipStream_t stream) {
    const float* S1 = (const float*)d_in[0];
    const float* S2 = (const float*)d_in[1];
    float* out = (float*)d_out;

    size_t needD  = (size_t)BATCH * N * N * sizeof(__half);
    size_t vecB   = (size_t)BATCH * N * 4;            // one per-col/per-row array
    size_t needT  = needD + 2 * vecB;                 // V + I            (R8 tier)
    size_t needT2 = needD + 6 * vecB;                 // + Vw,Uw,Cw,Rw    (R13 tier)

    emd_zero_kernel<<<1, 1, 0, stream>>>(out);

    if (ws_size >= needT2) {
        __half* D  = (__half*)d_ws;
        float*  V  = (float*)((char*)d_ws + needD);
        int*    I  = (int*)((char*)V + vecB);
        float*  Vw = (float*)((char*)I + vecB);
        float*  Uw = (float*)((char*)Vw + vecB);
        int*    Cw = (int*)((char*)Uw + vecB);
        int*    Rw = (int*)((char*)Cw + vecB);
        emd_dist_kernel<<<BATCH * N, 256, 0, stream>>>(S1, S2, D);
        emd_colmin_kernel<<<BATCH * 4, 256, 0, stream>>>(D, V, I);
        emd_auction_kernel<<<BATCH, 1024, 0, stream>>>(D, V, I, Vw, Uw, Cw, Rw);
        emd_jv_kernel<true, true><<<BATCH, 64, 0, stream>>>(
            S1, S2, D, Vw, nullptr, Uw, Cw, Rw, out);
    } else if (ws_size >= needT) {
        __half* D = (__half*)d_ws;
        float*  V = (float*)((char*)d_ws + needD);
        int*    I = (int*)((char*)V + vecB);
        emd_dist_kernel<<<BATCH * N, 256, 0, stream>>>(S1, S2, D);
        emd_colmin_kernel<<<BATCH * 4, 256, 0, stream>>>(D, V, I);
        emd_jv_kernel<true, false><<<BATCH, 64, 0, stream>>>(
            S1, S2, D, V, I, nullptr, nullptr, nullptr, out);
    } else {
        emd_jv_kernel<false, false><<<BATCH, 64, 0, stream>>>(
            S1, S2, nullptr, nullptr, nullptr, nullptr, nullptr, nullptr, out);
    }
}